// Round 8
// baseline (485.430 us; speedup 1.0000x reference)
//
#include <hip/hip_runtime.h>

#define T_LEN 1024
#define P_DIM 32
#define HOME_IDX 0
#define NCHUNK 32
#define CHUNK 32

// One wave (lanes 0-63) per batch; 1024 threads/block exist only for the
// parallel chunked backtrack (waves 1-15 sleep at the post-loop barrier).
//
// Forward pass = round-4 PROVEN structure (16 ds_bpermute broadcast, 16-q
// split per half, value/index split, depth-4 prefetch ring) with two cuts:
//
//  CUT 1 - winner-writes-psi (removes the index shfl_xor + cross-half min
//    from the serial chain): each half scans its local argmax ja against its
//    LOCAL max bv (scan overlaps shfl(bv) latency). After v1 = fmax(bv, ovv),
//    the lane pair (l, l^32) share one psi slot; the WINNING half writes it:
//      mine_wins = (h==0) ? (bv >= ovv) : (bv > ovv)
//    Ties go to half 0, which owns q in [0,16) -> exact first-index argmax
//    (global first max index lies in half 0 iff bv_0 == v1). Exactly one
//    lane of the pair writes; both compute cond identically from v1.
//  CUT 2 - U[t,0] via a second uniform-address global prefetch ring (same
//    128 B cacheline as the row the wave already fetches -> no extra HBM
//    traffic), removing the per-step __shfl(Ut,0) from the DS pipe.
//    u0c = U0ring + bias0: bit-identical operand order to the reference.
//
// DS pipe per step: 16 bpermute + 1 shfl_xor + 1 masked ds_write_u8.
//
// Exactness notes (harness-verified across rounds):
//  * NEG = finfo(f32).min/4; ulp(NEG) >> |A|<=0.01, so NEG + A == NEG; the
//    v=0 slice is NEG except q=HOME -> v0[p] = delta0h + A[0][p], a0 = 0.
//  * use1 = (v1 > v0) strict; cond = use1 || is_home; byte = cond?(a1|32):0.
//  * local argmax scan: c[j]==bv descending-j (fmax returns an input
//    bit-exactly; +-0 compare equal; inputs NaN-free) -> first index.
//  * delta0h update order preserved: (delta0h + A00) + (U[t,0] + bias0).
//
// Backtrack (PROVEN in round 4): 1023 backsteps in 32 chunks of <=32.
// Phase 1: 1024 threads build per-chunk (y,v)-maps for all 32 v=1 entry
// states. Phase 2: one thread composes maps from (last_p,1); v=0 absorbing
// at (0,0). Phase 3: 32 lanes re-walk their chunk from its true entry.
// Per-backstep rule identical to serial: if v: (y,v)=(byte&31,(byte>>5)&1)
// else (0,0); out[i] = new y.

__launch_bounds__(1024, 1)
__global__ void crf_viterbi_kernel(const float* __restrict__ U,
                                   const float* __restrict__ A,
                                   const float* __restrict__ bias,
                                   int* __restrict__ out)
{
    __shared__ unsigned char spsi[(T_LEN - 1) * P_DIM];   // 32736 B
    __shared__ unsigned char Mmap[NCHUNK * P_DIM];        // chunk maps
    __shared__ unsigned char ent[NCHUNK];                 // chunk entry states
    __shared__ int last_p_sh;

    const int tid = threadIdx.x;
    const int b   = blockIdx.x;
    int* __restrict__ outb = out + (size_t)b * T_LEN;

    if (tid < 64) {
        const int lane = tid;
        const int p    = lane & 31;
        const int h    = lane >> 5;
        const float NEG = -(3.4028234663852886e38f / 4.0f);

        // A fragment: A[q][p] for q = 16*h + j
        float Areg[16];
#pragma unroll
        for (int j = 0; j < 16; ++j)
            Areg[j] = A[(16 * h + j) * P_DIM + p];
        const float A0p    = A[p];        // A[HOME][p]
        const float A00    = A[0];        // A[HOME][HOME]
        const float bias_p = bias[p];
        const float bias0  = bias[0];
        const int   qb     = h << 6;      // bpermute byte base
        const int   q0     = h << 4;      // first q of this half
        const bool  is_home = (p == HOME_IDX);

        const float* __restrict__ Ub = U + (size_t)b * T_LEN * P_DIM;

        // t = 0 init
        const float u00 = Ub[p] + bias_p;
        float delta1  = is_home ? NEG : u00;     // v=1 slice, per-lane p
        float delta0h = Ub[HOME_IDX] + bias0;    // v=0 slice at HOME (uniform)

        // Prefetch rings, depth 4. Row t lives in slot (t-1)&3.
        float L0 = Ub[1 * P_DIM + p];
        float L1 = Ub[2 * P_DIM + p];
        float L2 = Ub[3 * P_DIM + p];
        float L3 = Ub[4 * P_DIM + p];
        // col-0 ring (uniform address; same cacheline as the row loads)
        float U0 = Ub[1 * P_DIM];
        float U1 = Ub[2 * P_DIM];
        float U2 = Ub[3 * P_DIM];
        float U3 = Ub[4 * P_DIM];

        float Ut_n = L0 + bias_p;          // for t = 1
        float u0_n = U0 + bias0;           // U[1,0] + bias0 (for t = 1)

#define STEP(t, Lc, Lr, Uc, Ur) do {                                           \
    const float Ut  = Ut_n;                                                    \
    const float u0c = u0_n;                                                    \
    Ut_n = (Lc) + bias_p;                                                      \
    u0_n = (Uc) + bias0;                                                       \
    { int tn = (t) + 4; if (tn > T_LEN - 1) tn = T_LEN - 1;                    \
      (Lr) = Ub[(size_t)tn * P_DIM + p];                                       \
      (Ur) = Ub[(size_t)tn * P_DIM]; }                                         \
    const int dsrc = __float_as_int(delta1);                                   \
    float c[16];                                                               \
    _Pragma("unroll")                                                          \
    for (int j = 0; j < 16; ++j)                                               \
        c[j] = __int_as_float(__builtin_amdgcn_ds_bpermute(qb + 4 * j, dsrc))  \
               + Areg[j];                                                      \
    /* value-only max tree over this half's 16 (v_max3-friendly, depth 3) */   \
    const float g0 = fmaxf(fmaxf(c[0],  c[1]),  c[2]);                         \
    const float g1 = fmaxf(fmaxf(c[3],  c[4]),  c[5]);                         \
    const float g2 = fmaxf(fmaxf(c[6],  c[7]),  c[8]);                         \
    const float g3 = fmaxf(fmaxf(c[9],  c[10]), c[11]);                        \
    const float g4 = fmaxf(fmaxf(c[12], c[13]), c[14]);                        \
    const float h0 = fmaxf(fmaxf(g0, g1), g2);                                 \
    const float h1 = fmaxf(fmaxf(g3, g4), c[15]);                              \
    const float bv = fmaxf(h0, h1);                                            \
    /* cross-half value combine (the ONLY on-chain DS after the train) */      \
    const float ovv = __shfl_xor(bv, 32);                                      \
    const float v1  = fmaxf(bv, ovv);                                          \
    const float v0  = delta0h + A0p;                                           \
    const bool  use1 = (v1 > v0);              /* strict, as reference */      \
    const bool  cond = use1 || is_home;                                        \
    const float sel  = cond ? v1 : v0;                                         \
    const float dn1  = sel + Ut;                                               \
    delta0h = (delta0h + A00) + u0c;                                           \
    /* local argmax vs LOCAL max bv (overlaps shfl latency): first j == bv */  \
    int ja = 15;                                                               \
    _Pragma("unroll")                                                          \
    for (int j = 14; j >= 0; --j)                                              \
        if (c[j] == bv) ja = j;                                                \
    const int bt = cond ? ((q0 + ja) | 32) : 0;                                \
    /* winner-writes-psi: ties -> half 0 (owns smaller q) => first-index */    \
    const bool mine_wins = h ? (bv > ovv) : (bv >= ovv);                       \
    if (mine_wins)                                                             \
        spsi[(size_t)((t) - 1) * P_DIM + p] = (unsigned char)bt;               \
    delta1 = dn1;                                                              \
} while (0)

        STEP(1, L1, L0, U1, U0);
        STEP(2, L2, L1, U2, U1);
        STEP(3, L3, L2, U3, U2);
        for (int t = 4; t <= T_LEN - 4; t += 4) {
            STEP(t + 0, L0, L3, U0, U3);
            STEP(t + 1, L1, L0, U1, U0);
            STEP(t + 2, L2, L1, U2, U1);
            STEP(t + 3, L3, L2, U3, U2);
        }
#undef STEP

        // last_p = argmax_p delta_T[:,1], first index wins (lexicographic
        // butterfly; lanes 32..63 duplicate p = lane-32, idx tie-break wins).
        float mv = delta1;
        int   mi = p;
#pragma unroll
        for (int m = 16; m >= 1; m >>= 1) {
            float ov = __shfl_xor(mv, m);
            int   oi = __shfl_xor(mi, m);
            bool take = (ov > mv) || ((ov == mv) && (oi < mi));
            mv = take ? ov : mv;
            mi = take ? oi : mi;
        }
        if (lane == 0) {
            outb[T_LEN - 1] = mi;
            last_p_sh = mi;
        }
    }

    __syncthreads();   // psi + last_p visible to all 16 waves

    // Phase 1: per-chunk maps. Chunk c covers backsteps i in
    // [32c, min(32c+32, 1023)). Thread (c = tid>>5, pp = tid&31) walks from
    // hypothetical entry (pp, v=1).
    {
        const int c  = tid >> 5;
        const int pp = tid & 31;
        const int i_hi = min((c + 1) * CHUNK, T_LEN - 1);
        const int i_lo = c * CHUNK;
        int y = pp, v = 1;
        for (int i = i_hi - 1; i >= i_lo; --i) {
            const int bt = spsi[i * P_DIM + y];
            const int py = v ? (bt & 31) : 0;
            const int nv = v ? ((bt >> 5) & 1) : 0;
            y = py; v = nv;
        }
        Mmap[c * P_DIM + pp] = (unsigned char)(y | (v << 5));
    }
    __syncthreads();

    // Phase 2: compose maps from the top to get each chunk's true entry state.
    if (tid == 0) {
        int y = last_p_sh, v = 1;
        for (int c = NCHUNK - 1; c >= 0; --c) {
            ent[c] = (unsigned char)(y | (v << 5));
            if (v) {
                const int m = Mmap[c * P_DIM + y];
                y = m & 31;
                v = (m >> 5) & 1;
            } else {
                y = 0; v = 0;
            }
        }
    }
    __syncthreads();

    // Phase 3: 32 lanes re-walk their chunk from the true entry, emitting out.
    if (tid < NCHUNK) {
        const int c = tid;
        const int i_hi = min((c + 1) * CHUNK, T_LEN - 1);
        const int i_lo = c * CHUNK;
        const int e = ent[c];
        int y = e & 31;
        int v = (e >> 5) & 1;
        for (int i = i_hi - 1; i >= i_lo; --i) {
            const int bt = spsi[i * P_DIM + y];
            const int py = v ? (bt & 31) : 0;
            const int nv = v ? ((bt >> 5) & 1) : 0;
            outb[i] = py;
            y = py; v = nv;
        }
    }
}

extern "C" void kernel_launch(void* const* d_in, const int* in_sizes, int n_in,
                              void* d_out, int out_size, void* d_ws, size_t ws_size,
                              hipStream_t stream) {
    const float* U    = (const float*)d_in[0];   // (B, T, P) f32
    const float* A    = (const float*)d_in[1];   // (P, P)    f32
    const float* bias = (const float*)d_in[2];   // (P,)      f32
    int* out = (int*)d_out;                      // (B, T)    int32

    const int B = in_sizes[0] / (T_LEN * P_DIM);
    crf_viterbi_kernel<<<B, 1024, 0, stream>>>(U, A, bias, out);
}

// Round 9
// 392.599 us; speedup vs baseline: 1.2365x; 1.2365x over previous
//
#include <hip/hip_runtime.h>

#define T_LEN 1024
#define P_DIM 32
#define HOME_IDX 0
#define NCHUNK 32
#define CHUNK 32

// One wave (lanes 0-63) per batch; 1024 threads/block exist only for the
// parallel chunked backtrack (waves 1-15 sleep at the post-loop barrier).
//
// Forward pass = round-4 PROVEN structure (16 ds_bpermute broadcast, 16-q
// split per half, value/index split, depth-4 prefetch ring, __shfl(Ut,0)
// for the u0 broadcast) + exactly ONE change, CUT 1 (harness-verified
// correct in r8, isolated here after r8's CUT 2 regression):
//
//  CUT 1 - winner-writes-psi: removes the index shfl_xor + cross-half min
//    from the serial chain. Each half scans its local argmax ja against its
//    LOCAL max bv (the scan overlaps the value-shfl's latency). After
//    v1 = fmax(bv, ovv), the lane pair (l, l^32) share one psi slot; the
//    WINNING half writes it:
//      mine_wins = (h==0) ? (bv >= ovv) : (bv > ovv)
//    Ties go to half 0, which owns q in [0,16) -> exact first-index argmax.
//    Exactly one lane of the pair writes; both compute cond from v1.
//
//  r8 lesson (CUT 2 reverted): a uniform-address global ring for U[t,0]
//    scalarizes to SMEM loads -> +8 MB FETCH (separate K$ lines) and
//    conservative lgkmcnt(0) drains (SMEM+DS share lgkmcnt, SMEM completes
//    out of order) -> 515 us. u0 stays on the proven __shfl(Ut_n, 0).
//
// Exactness notes (harness-verified across rounds):
//  * NEG = finfo(f32).min/4; ulp(NEG) >> |A|<=0.01, so NEG + A == NEG; the
//    v=0 slice is NEG except q=HOME -> v0[p] = delta0h + A[0][p], a0 = 0.
//  * use1 = (v1 > v0) strict; cond = use1 || is_home; byte = cond?(a1|32):0.
//  * local argmax scan: c[j]==bv descending-j (fmax returns an input
//    bit-exactly; +-0 compare equal; inputs NaN-free) -> first index.
//  * delta0h update order preserved: (delta0h + A00) + (u[t,0] + bias0).
//
// Backtrack (PROVEN in round 4): 1023 backsteps in 32 chunks of <=32.
// Phase 1: 1024 threads build per-chunk (y,v)-maps for all 32 v=1 entry
// states. Phase 2: one thread composes maps from (last_p,1); v=0 absorbing
// at (0,0). Phase 3: 32 lanes re-walk their chunk from its true entry.
// Per-backstep rule identical to serial: if v: (y,v)=(byte&31,(byte>>5)&1)
// else (0,0); out[i] = new y.

__launch_bounds__(1024, 1)
__global__ void crf_viterbi_kernel(const float* __restrict__ U,
                                   const float* __restrict__ A,
                                   const float* __restrict__ bias,
                                   int* __restrict__ out)
{
    __shared__ unsigned char spsi[(T_LEN - 1) * P_DIM];   // 32736 B
    __shared__ unsigned char Mmap[NCHUNK * P_DIM];        // chunk maps
    __shared__ unsigned char ent[NCHUNK];                 // chunk entry states
    __shared__ int last_p_sh;

    const int tid = threadIdx.x;
    const int b   = blockIdx.x;
    int* __restrict__ outb = out + (size_t)b * T_LEN;

    if (tid < 64) {
        const int lane = tid;
        const int p    = lane & 31;
        const int h    = lane >> 5;
        const float NEG = -(3.4028234663852886e38f / 4.0f);

        // A fragment: A[q][p] for q = 16*h + j
        float Areg[16];
#pragma unroll
        for (int j = 0; j < 16; ++j)
            Areg[j] = A[(16 * h + j) * P_DIM + p];
        const float A0p    = A[p];        // A[HOME][p]
        const float A00    = A[0];        // A[HOME][HOME]
        const float bias_p = bias[p];
        const float bias0  = bias[0];
        const int   qb     = h << 6;      // bpermute byte base
        const int   q0     = h << 4;      // first q of this half
        const bool  is_home = (p == HOME_IDX);

        const float* __restrict__ Ub = U + (size_t)b * T_LEN * P_DIM;

        // t = 0 init
        const float u00 = Ub[p] + bias_p;
        float delta1  = is_home ? NEG : u00;     // v=1 slice, per-lane p
        float delta0h = Ub[HOME_IDX] + bias0;    // v=0 slice at HOME (uniform)

        // Prefetch ring, depth 4. Row t lives in slot (t-1)&3.
        float L0 = Ub[1 * P_DIM + p];
        float L1 = Ub[2 * P_DIM + p];
        float L2 = Ub[3 * P_DIM + p];
        float L3 = Ub[4 * P_DIM + p];

        float Ut_n = L0 + bias_p;          // for t = 1
        float u0_n = __shfl(Ut_n, 0);      // u[t,0] + bias0, broadcast

#define STEP(t, Lc, Lr) do {                                                   \
    const float Ut  = Ut_n;                                                    \
    const float u0c = u0_n;                                                    \
    Ut_n = (Lc) + bias_p;                                                      \
    u0_n = __shfl(Ut_n, 0);                                                    \
    { int tn = (t) + 4; if (tn > T_LEN - 1) tn = T_LEN - 1;                    \
      (Lr) = Ub[(size_t)tn * P_DIM + p]; }                                     \
    const int dsrc = __float_as_int(delta1);                                   \
    float c[16];                                                               \
    _Pragma("unroll")                                                          \
    for (int j = 0; j < 16; ++j)                                               \
        c[j] = __int_as_float(__builtin_amdgcn_ds_bpermute(qb + 4 * j, dsrc))  \
               + Areg[j];                                                      \
    /* value-only max tree over this half's 16 (v_max3-friendly, depth 3) */   \
    const float g0 = fmaxf(fmaxf(c[0],  c[1]),  c[2]);                         \
    const float g1 = fmaxf(fmaxf(c[3],  c[4]),  c[5]);                         \
    const float g2 = fmaxf(fmaxf(c[6],  c[7]),  c[8]);                         \
    const float g3 = fmaxf(fmaxf(c[9],  c[10]), c[11]);                        \
    const float g4 = fmaxf(fmaxf(c[12], c[13]), c[14]);                        \
    const float h0 = fmaxf(fmaxf(g0, g1), g2);                                 \
    const float h1 = fmaxf(fmaxf(g3, g4), c[15]);                              \
    const float bv = fmaxf(h0, h1);                                            \
    /* cross-half value combine (the ONLY on-chain DS after the train) */      \
    const float ovv = __shfl_xor(bv, 32);                                      \
    const float v1  = fmaxf(bv, ovv);                                          \
    const float v0  = delta0h + A0p;                                           \
    const bool  use1 = (v1 > v0);              /* strict, as reference */      \
    const bool  cond = use1 || is_home;                                        \
    const float sel  = cond ? v1 : v0;                                         \
    const float dn1  = sel + Ut;                                               \
    delta0h = (delta0h + A00) + u0c;                                           \
    /* local argmax vs LOCAL max bv (overlaps shfl latency): first j == bv */  \
    int ja = 15;                                                               \
    _Pragma("unroll")                                                          \
    for (int j = 14; j >= 0; --j)                                              \
        if (c[j] == bv) ja = j;                                                \
    const int bt = cond ? ((q0 + ja) | 32) : 0;                                \
    /* winner-writes-psi: ties -> half 0 (owns smaller q) => first-index */    \
    const bool mine_wins = h ? (bv > ovv) : (bv >= ovv);                       \
    if (mine_wins)                                                             \
        spsi[(size_t)((t) - 1) * P_DIM + p] = (unsigned char)bt;               \
    delta1 = dn1;                                                              \
} while (0)

        STEP(1, L1, L0);
        STEP(2, L2, L1);
        STEP(3, L3, L2);
        for (int t = 4; t <= T_LEN - 4; t += 4) {
            STEP(t + 0, L0, L3);
            STEP(t + 1, L1, L0);
            STEP(t + 2, L2, L1);
            STEP(t + 3, L3, L2);
        }
#undef STEP

        // last_p = argmax_p delta_T[:,1], first index wins (lexicographic
        // butterfly; lanes 32..63 duplicate p = lane-32, idx tie-break wins).
        float mv = delta1;
        int   mi = p;
#pragma unroll
        for (int m = 16; m >= 1; m >>= 1) {
            float ov = __shfl_xor(mv, m);
            int   oi = __shfl_xor(mi, m);
            bool take = (ov > mv) || ((ov == mv) && (oi < mi));
            mv = take ? ov : mv;
            mi = take ? oi : mi;
        }
        if (lane == 0) {
            outb[T_LEN - 1] = mi;
            last_p_sh = mi;
        }
    }

    __syncthreads();   // psi + last_p visible to all 16 waves

    // Phase 1: per-chunk maps. Chunk c covers backsteps i in
    // [32c, min(32c+32, 1023)). Thread (c = tid>>5, pp = tid&31) walks from
    // hypothetical entry (pp, v=1).
    {
        const int c  = tid >> 5;
        const int pp = tid & 31;
        const int i_hi = min((c + 1) * CHUNK, T_LEN - 1);
        const int i_lo = c * CHUNK;
        int y = pp, v = 1;
        for (int i = i_hi - 1; i >= i_lo; --i) {
            const int bt = spsi[i * P_DIM + y];
            const int py = v ? (bt & 31) : 0;
            const int nv = v ? ((bt >> 5) & 1) : 0;
            y = py; v = nv;
        }
        Mmap[c * P_DIM + pp] = (unsigned char)(y | (v << 5));
    }
    __syncthreads();

    // Phase 2: compose maps from the top to get each chunk's true entry state.
    if (tid == 0) {
        int y = last_p_sh, v = 1;
        for (int c = NCHUNK - 1; c >= 0; --c) {
            ent[c] = (unsigned char)(y | (v << 5));
            if (v) {
                const int m = Mmap[c * P_DIM + y];
                y = m & 31;
                v = (m >> 5) & 1;
            } else {
                y = 0; v = 0;
            }
        }
    }
    __syncthreads();

    // Phase 3: 32 lanes re-walk their chunk from the true entry, emitting out.
    if (tid < NCHUNK) {
        const int c = tid;
        const int i_hi = min((c + 1) * CHUNK, T_LEN - 1);
        const int i_lo = c * CHUNK;
        const int e = ent[c];
        int y = e & 31;
        int v = (e >> 5) & 1;
        for (int i = i_hi - 1; i >= i_lo; --i) {
            const int bt = spsi[i * P_DIM + y];
            const int py = v ? (bt & 31) : 0;
            const int nv = v ? ((bt >> 5) & 1) : 0;
            outb[i] = py;
            y = py; v = nv;
        }
    }
}

extern "C" void kernel_launch(void* const* d_in, const int* in_sizes, int n_in,
                              void* d_out, int out_size, void* d_ws, size_t ws_size,
                              hipStream_t stream) {
    const float* U    = (const float*)d_in[0];   // (B, T, P) f32
    const float* A    = (const float*)d_in[1];   // (P, P)    f32
    const float* bias = (const float*)d_in[2];   // (P,)      f32
    int* out = (int*)d_out;                      // (B, T)    int32

    const int B = in_sizes[0] / (T_LEN * P_DIM);
    crf_viterbi_kernel<<<B, 1024, 0, stream>>>(U, A, bias, out);
}

// Round 10
// 309.155 us; speedup vs baseline: 1.5702x; 1.2699x over previous
//
#include <hip/hip_runtime.h>

#define T_LEN 1024
#define P_DIM 32
#define HOME_IDX 0
#define NCHUNK 32
#define CHUNK 32

// One wave (lanes 0-63) per batch; 1024 threads/block exist only for the
// parallel chunked backtrack (waves 1-15 sleep at the post-loop barrier).
//
// Base = round-4 PROVEN kernel (274 us; best verified). r9 taught that the
// r4 idiosyncrasies (unconditional psi write, scan-vs-v1 index path) must be
// preserved verbatim. THIS round's single change: the delta broadcast.
//
//   r4: 16x ds_bpermute per step (19 wave64 DS ops/step total).
//   r10: restage via LDS — sdelta[p] = dn1 (one ds_write_b32; lanes l and
//        l+32 write the same value to the same address — r7-proven benign),
//        then 4 uniform-address ds_read_b128 of THIS HALF's 16 q's
//        (half-wave-uniform address => LDS broadcast; 2 distinct addresses
//        across the wave is free aliasing). Write->read RAW is handled by
//        the in-order DS pipe within a wave, no barrier (r7-proven).
//        DS ops/step: 19 -> 9. Per-lane VALU unchanged from r4 (16 adds,
//        16-wide tree, 16-scan) — r7's VALU doubling is NOT repeated.
//   Arithmetic bit-identical to r4: c[j] = delta_prev[16h+j] + Areg[j].
//
// Exactness notes (harness-verified across rounds):
//  * NEG = finfo(f32).min/4; ulp(NEG) >> |A|<=0.01, so NEG + A == NEG; the
//    v=0 slice is NEG except q=HOME -> v0[p] = delta0h + A[0][p], a0 = 0.
//  * use1 = (v1 > v0) strict, matching the reference.
//  * argmax off-path: equality scan c[j]==v1 (fmax returns an input
//    bit-exactly; +-0 compare equal; inputs NaN-free), descending-j scan +
//    cross-half min-index (sentinel 99 > any valid q) => first-index.
//  * delta0h update order preserved: (delta0h + A00) + (u[t,0] + bias0).
//
// Backtrack (PROVEN in round 4): 1023 backsteps in 32 chunks of <=32.
// Phase 1: 1024 threads build per-chunk (y,v)-maps for all 32 v=1 entry
// states. Phase 2: one thread composes maps from (last_p,1); v=0 absorbing
// at (0,0). Phase 3: 32 lanes re-walk their chunk from its true entry.
// Per-backstep rule identical to serial: if v: (y,v)=(byte&31,(byte>>5)&1)
// else (0,0); out[i] = new y.

__launch_bounds__(1024, 1)
__global__ void crf_viterbi_kernel(const float* __restrict__ U,
                                   const float* __restrict__ A,
                                   const float* __restrict__ bias,
                                   int* __restrict__ out)
{
    __shared__ __align__(16) float sdelta[P_DIM];         // 128 B delta stage
    __shared__ unsigned char spsi[(T_LEN - 1) * P_DIM];   // 32736 B
    __shared__ unsigned char Mmap[NCHUNK * P_DIM];        // chunk maps
    __shared__ unsigned char ent[NCHUNK];                 // chunk entry states
    __shared__ int last_p_sh;

    const int tid = threadIdx.x;
    const int b   = blockIdx.x;
    int* __restrict__ outb = out + (size_t)b * T_LEN;

    if (tid < 64) {
        const int lane = tid;
        const int p    = lane & 31;
        const int h    = lane >> 5;
        const float NEG = -(3.4028234663852886e38f / 4.0f);

        // A fragment: A[q][p] for q = 16*h + j
        float Areg[16];
#pragma unroll
        for (int j = 0; j < 16; ++j)
            Areg[j] = A[(16 * h + j) * P_DIM + p];
        const float A0p    = A[p];        // A[HOME][p]
        const float A00    = A[0];        // A[HOME][HOME]
        const float bias_p = bias[p];
        const float bias0  = bias[0];
        const int   q0     = h << 4;      // first q of this half
        const bool  is_home = (p == HOME_IDX);

        const float4* __restrict__ sd4 = (const float4*)sdelta;

        const float* __restrict__ Ub = U + (size_t)b * T_LEN * P_DIM;

        // t = 0 init
        const float u00 = Ub[p] + bias_p;
        float delta1  = is_home ? NEG : u00;     // v=1 slice, per-lane p
        float delta0h = Ub[HOME_IDX] + bias0;    // v=0 slice at HOME (uniform)

        // Prefetch ring, depth 4. Row t lives in slot (t-1)&3.
        float L0 = Ub[1 * P_DIM + p];
        float L1 = Ub[2 * P_DIM + p];
        float L2 = Ub[3 * P_DIM + p];
        float L3 = Ub[4 * P_DIM + p];

        float Ut_n = L0 + bias_p;          // for t = 1
        float u0_n = __shfl(Ut_n, 0);      // u[t,0] + bias0, broadcast

        // Stage initial delta; read this half's 16 q's (in-order DS pipe).
        sdelta[p] = delta1;
        float4 R0 = sd4[4 * h + 0];
        float4 R1 = sd4[4 * h + 1];
        float4 R2 = sd4[4 * h + 2];
        float4 R3 = sd4[4 * h + 3];

#define STEP(t, Lc, Lr) do {                                                   \
    const float Ut  = Ut_n;                                                    \
    const float u0c = u0_n;                                                    \
    Ut_n = (Lc) + bias_p;                                                      \
    u0_n = __shfl(Ut_n, 0);                                                    \
    { int tn = (t) + 4; if (tn > T_LEN - 1) tn = T_LEN - 1;                    \
      (Lr) = Ub[(size_t)tn * P_DIM + p]; }                                     \
    float c[16];                                                               \
    c[0]  = R0.x + Areg[0];  c[1]  = R0.y + Areg[1];                           \
    c[2]  = R0.z + Areg[2];  c[3]  = R0.w + Areg[3];                           \
    c[4]  = R1.x + Areg[4];  c[5]  = R1.y + Areg[5];                           \
    c[6]  = R1.z + Areg[6];  c[7]  = R1.w + Areg[7];                           \
    c[8]  = R2.x + Areg[8];  c[9]  = R2.y + Areg[9];                           \
    c[10] = R2.z + Areg[10]; c[11] = R2.w + Areg[11];                          \
    c[12] = R3.x + Areg[12]; c[13] = R3.y + Areg[13];                          \
    c[14] = R3.z + Areg[14]; c[15] = R3.w + Areg[15];                          \
    /* value-only max tree over this half's 16 (v_max3-friendly, depth 3) */   \
    const float g0 = fmaxf(fmaxf(c[0],  c[1]),  c[2]);                         \
    const float g1 = fmaxf(fmaxf(c[3],  c[4]),  c[5]);                         \
    const float g2 = fmaxf(fmaxf(c[6],  c[7]),  c[8]);                         \
    const float g3 = fmaxf(fmaxf(c[9],  c[10]), c[11]);                        \
    const float g4 = fmaxf(fmaxf(c[12], c[13]), c[14]);                        \
    const float h0 = fmaxf(fmaxf(g0, g1), g2);                                 \
    const float h1 = fmaxf(fmaxf(g3, g4), c[15]);                              \
    const float bv = fmaxf(h0, h1);                                            \
    /* cross-half value combine */                                             \
    const float ovv = __shfl_xor(bv, 32);                                      \
    const float v1  = fmaxf(bv, ovv);                                          \
    const float v0  = delta0h + A0p;                                           \
    const bool  use1 = (v1 > v0);              /* strict, as reference */      \
    const bool  cond = use1 || is_home;                                        \
    const float sel  = cond ? v1 : v0;                                         \
    const float dn1  = sel + Ut;                                               \
    delta0h = (delta0h + A00) + u0c;                                           \
    /* restage delta + issue next step's reads (in-order DS, no barrier); */   \
    /* placed BEFORE the index path so the reads aren't queued behind it */    \
    sdelta[p] = dn1;                                                           \
    R0 = sd4[4 * h + 0];                                                       \
    R1 = sd4[4 * h + 1];                                                       \
    R2 = sd4[4 * h + 2];                                                       \
    R3 = sd4[4 * h + 3];                                                       \
    /* index path (r4 VERBATIM): first q with c == v1, cross-half min */       \
    int ia = 99;                                                               \
    _Pragma("unroll")                                                          \
    for (int j = 15; j >= 0; --j)                                              \
        if (c[j] == v1) ia = q0 + j;                                           \
    const int oia = __shfl_xor(ia, 32);                                        \
    const int a1  = (ia < oia) ? ia : oia;                                     \
    const int bt  = cond ? (a1 | 32) : 0;                                      \
    spsi[(size_t)((t) - 1) * P_DIM + p] = (unsigned char)bt;                   \
    delta1 = dn1;                                                              \
} while (0)

        STEP(1, L1, L0);
        STEP(2, L2, L1);
        STEP(3, L3, L2);
        for (int t = 4; t <= T_LEN - 4; t += 4) {
            STEP(t + 0, L0, L3);
            STEP(t + 1, L1, L0);
            STEP(t + 2, L2, L1);
            STEP(t + 3, L3, L2);
        }
#undef STEP

        // last_p = argmax_p delta_T[:,1], first index wins (lexicographic
        // butterfly; lanes 32..63 duplicate p = lane-32, idx tie-break wins).
        float mv = delta1;
        int   mi = p;
#pragma unroll
        for (int m = 16; m >= 1; m >>= 1) {
            float ov = __shfl_xor(mv, m);
            int   oi = __shfl_xor(mi, m);
            bool take = (ov > mv) || ((ov == mv) && (oi < mi));
            mv = take ? ov : mv;
            mi = take ? oi : mi;
        }
        if (lane == 0) {
            outb[T_LEN - 1] = mi;
            last_p_sh = mi;
        }
    }

    __syncthreads();   // psi + last_p visible to all 16 waves

    // Phase 1: per-chunk maps. Chunk c covers backsteps i in
    // [32c, min(32c+32, 1023)). Thread (c = tid>>5, pp = tid&31) walks from
    // hypothetical entry (pp, v=1).
    {
        const int c  = tid >> 5;
        const int pp = tid & 31;
        const int i_hi = min((c + 1) * CHUNK, T_LEN - 1);
        const int i_lo = c * CHUNK;
        int y = pp, v = 1;
        for (int i = i_hi - 1; i >= i_lo; --i) {
            const int bt = spsi[i * P_DIM + y];
            const int py = v ? (bt & 31) : 0;
            const int nv = v ? ((bt >> 5) & 1) : 0;
            y = py; v = nv;
        }
        Mmap[c * P_DIM + pp] = (unsigned char)(y | (v << 5));
    }
    __syncthreads();

    // Phase 2: compose maps from the top to get each chunk's true entry state.
    if (tid == 0) {
        int y = last_p_sh, v = 1;
        for (int c = NCHUNK - 1; c >= 0; --c) {
            ent[c] = (unsigned char)(y | (v << 5));
            if (v) {
                const int m = Mmap[c * P_DIM + y];
                y = m & 31;
                v = (m >> 5) & 1;
            } else {
                y = 0; v = 0;
            }
        }
    }
    __syncthreads();

    // Phase 3: 32 lanes re-walk their chunk from the true entry, emitting out.
    if (tid < NCHUNK) {
        const int c = tid;
        const int i_hi = min((c + 1) * CHUNK, T_LEN - 1);
        const int i_lo = c * CHUNK;
        const int e = ent[c];
        int y = e & 31;
        int v = (e >> 5) & 1;
        for (int i = i_hi - 1; i >= i_lo; --i) {
            const int bt = spsi[i * P_DIM + y];
            const int py = v ? (bt & 31) : 0;
            const int nv = v ? ((bt >> 5) & 1) : 0;
            outb[i] = py;
            y = py; v = nv;
        }
    }
}

extern "C" void kernel_launch(void* const* d_in, const int* in_sizes, int n_in,
                              void* d_out, int out_size, void* d_ws, size_t ws_size,
                              hipStream_t stream) {
    const float* U    = (const float*)d_in[0];   // (B, T, P) f32
    const float* A    = (const float*)d_in[1];   // (P, P)    f32
    const float* bias = (const float*)d_in[2];   // (P,)      f32
    int* out = (int*)d_out;                      // (B, T)    int32

    const int B = in_sizes[0] / (T_LEN * P_DIM);
    crf_viterbi_kernel<<<B, 1024, 0, stream>>>(U, A, bias, out);
}